// Round 1
// baseline (764.328 us; speedup 1.0000x reference)
//
#include <hip/hip_runtime.h>
#include <math.h>

#define BB 8
#define CC 3
#define HH 256
#define WW 256
#define NF 18
#define KSZ 37
#define PD 18

#define DWT_OFF 0
#define GAB_OFF (8*12*128*128)                 /* 1572864 */
#define FFT_OFF (GAB_OFF + 8*54*256*256)       /* 29884416 */

// ---------------------------------------------------------------- Haar DWT
__global__ __launch_bounds__(256) void haar_dwt_kernel(
    const float* __restrict__ x, float* __restrict__ out) {
  int idx = blockIdx.x * 256 + threadIdx.x;       // 8*3*128*128 = 393216
  if (idx >= BB * CC * 128 * 128) return;
  int j  = idx & 127;
  int i  = (idx >> 7) & 127;
  int bc = idx >> 14;                             // b*3 + c
  const float* xp = x + (size_t)bc * (HH * WW);
  float2 top = *reinterpret_cast<const float2*>(&xp[(2 * i) * WW + 2 * j]);
  float2 bot = *reinterpret_cast<const float2*>(&xp[(2 * i + 1) * WW + 2 * j]);
  float a = top.x, b = top.y, c = bot.x, d = bot.y;
  int bI = bc / 3, cI = bc % 3;
  float* op = out + DWT_OFF + ((size_t)(bI * 12 + cI * 4) * 128 + i) * 128 + j;
  op[0]     = (a + b + c + d) * 0.5f;
  op[16384] = (a + b - c - d) * 0.5f;
  op[32768] = (a - b + c - d) * 0.5f;
  op[49152] = (a - b - c + d) * 0.5f;
}

// ---------------------------------------------------------------- Gabor conv
// One block per (b, c, 32x32 tile). Computes all 18 output channels for the
// tile (filter blocks of 6). Patch 68x68 staged in LDS, stride 72 (2-way
// bank pattern = free).
__global__ __launch_bounds__(256) void gabor_conv_kernel(
    const float* __restrict__ x, const float* __restrict__ wk,
    float* __restrict__ out) {
  __shared__ float patch[68 * 72];
  const int tileX = (blockIdx.x & 7) * 32;
  const int tileY = (blockIdx.x >> 3) * 32;
  const int c = blockIdx.y;
  const int b = blockIdx.z;
  const float* xp = x + (size_t)(b * CC + c) * (HH * WW);
  const int tid = threadIdx.x;

  for (int idx = tid; idx < 68 * 68; idx += 256) {
    int py = idx / 68, px = idx - py * 68;
    int gy = tileY + py - PD;
    int gx = tileX + px - PD;
    float v = 0.0f;
    if ((unsigned)gy < 256u && (unsigned)gx < 256u) v = xp[gy * WW + gx];
    patch[py * 72 + px] = v;
  }
  __syncthreads();

  const int row = tid >> 3;      // 0..31
  const int cg  = tid & 7;       // 0..7
  const int xb  = cg * 4;
  float* outbase = out + GAB_OFF + (size_t)(b * 54 + c * 18) * (HH * WW)
                 + (size_t)(tileY + row) * WW + tileX + xb;

  for (int fb = 0; fb < 3; ++fb) {
    float acc[6][4];
#pragma unroll
    for (int f = 0; f < 6; ++f) {
      acc[f][0] = 0.f; acc[f][1] = 0.f; acc[f][2] = 0.f; acc[f][3] = 0.f;
    }
    for (int ky = 0; ky < KSZ; ++ky) {
      float win[40];
      const float4* lp =
          reinterpret_cast<const float4*>(&patch[(row + ky) * 72 + xb]);
#pragma unroll
      for (int q = 0; q < 10; ++q) {
        float4 v = lp[q];
        win[q * 4 + 0] = v.x; win[q * 4 + 1] = v.y;
        win[q * 4 + 2] = v.z; win[q * 4 + 3] = v.w;
      }
      const float* wrow = wk + (size_t)(fb * 6) * (KSZ * KSZ) + ky * KSZ;
#pragma unroll
      for (int f = 0; f < 6; ++f) {
#pragma unroll
        for (int kx = 0; kx < KSZ; ++kx) {
          float wv = wrow[f * (KSZ * KSZ) + kx];
          acc[f][0] += win[kx + 0] * wv;
          acc[f][1] += win[kx + 1] * wv;
          acc[f][2] += win[kx + 2] * wv;
          acc[f][3] += win[kx + 3] * wv;
        }
      }
    }
#pragma unroll
    for (int f = 0; f < 6; ++f) {
      float4 o = make_float4(acc[f][0], acc[f][1], acc[f][2], acc[f][3]);
      *reinterpret_cast<float4*>(outbase + (size_t)(fb * 6 + f) * (HH * WW)) = o;
    }
  }
}

// ---------------------------------------------------------------- FFT pass A
// One 64-thread block per row. Real input 256 -> full 256-pt FFT, store bins
// 0..128 (interleaved complex, row stride 258 floats) into staging.
__global__ __launch_bounds__(64) void fft_rows_kernel(
    const float* __restrict__ x, float* __restrict__ stg) {
  __shared__ float re[256], im[256];
  const int rowid = blockIdx.x;            // (b*3+c)*256 + y
  const float* xr = x + (size_t)rowid * 256;
  const int t = threadIdx.x;

#pragma unroll
  for (int q = 0; q < 4; ++q) {
    int i = t + q * 64;
    int br = __brev((unsigned)i) >> 24;
    re[br] = xr[i];
    im[br] = 0.0f;
  }
  __syncthreads();

  for (int s = 1; s <= 8; ++s) {
    int half = 1 << (s - 1);
#pragma unroll
    for (int q = 0; q < 2; ++q) {
      int j = t + q * 64;                  // 128 butterflies
      int g = j >> (s - 1);
      int p = j & (half - 1);
      int i1 = (g << s) + p;
      int i2 = i1 + half;
      float ang = -(float)M_PI * (float)p / (float)half;
      float sn, cs;
      sincosf(ang, &sn, &cs);
      float r2 = re[i2], m2 = im[i2];
      float tr = r2 * cs - m2 * sn;
      float ti = r2 * sn + m2 * cs;
      float r1 = re[i1], m1 = im[i1];
      re[i2] = r1 - tr; im[i2] = m1 - ti;
      re[i1] = r1 + tr; im[i1] = m1 + ti;
    }
    __syncthreads();
  }

  float* sr = stg + (size_t)rowid * 258;
#pragma unroll
  for (int q = 0; q < 3; ++q) {
    int k = t + q * 64;
    if (k <= 128) {
      sr[2 * k]     = re[k];
      sr[2 * k + 1] = im[k];
    }
  }
}

// ---------------------------------------------------------------- FFT pass B
// One 64-thread block per (b,c,k). k<129: column FFT + mag/phase; k>=129:
// write zero padding.
__global__ __launch_bounds__(64) void fft_cols_kernel(
    const float* __restrict__ stg, float* __restrict__ outf) {
  const int k  = blockIdx.x & 255;
  const int bc = blockIdx.x >> 8;          // 0..23
  const int b  = bc / 3;
  const int c  = bc - b * 3;
  const int t  = threadIdx.x;
  float* magp = outf + (size_t)(b * 6 + c) * (HH * WW);
  float* php  = outf + (size_t)(b * 6 + c + 3) * (HH * WW);

  if (k >= 129) {
#pragma unroll
    for (int q = 0; q < 4; ++q) {
      int u = t + q * 64;
      magp[(size_t)u * WW + k] = 0.0f;
      php[(size_t)u * WW + k]  = 0.0f;
    }
    return;
  }

  __shared__ float re[256], im[256];
  const float* sp = stg + (size_t)bc * (256 * 258);
#pragma unroll
  for (int q = 0; q < 4; ++q) {
    int y = t + q * 64;
    int br = __brev((unsigned)y) >> 24;
    re[br] = sp[(size_t)y * 258 + 2 * k];
    im[br] = sp[(size_t)y * 258 + 2 * k + 1];
  }
  __syncthreads();

  for (int s = 1; s <= 8; ++s) {
    int half = 1 << (s - 1);
#pragma unroll
    for (int q = 0; q < 2; ++q) {
      int j = t + q * 64;
      int g = j >> (s - 1);
      int p = j & (half - 1);
      int i1 = (g << s) + p;
      int i2 = i1 + half;
      float ang = -(float)M_PI * (float)p / (float)half;
      float sn, cs;
      sincosf(ang, &sn, &cs);
      float r2 = re[i2], m2 = im[i2];
      float tr = r2 * cs - m2 * sn;
      float ti = r2 * sn + m2 * cs;
      float r1 = re[i1], m1 = im[i1];
      re[i2] = r1 - tr; im[i2] = m1 - ti;
      re[i1] = r1 + tr; im[i1] = m1 + ti;
    }
    __syncthreads();
  }

  const float scale = 1.0f / 256.0f;       // ortho norm: /sqrt(256*256)
#pragma unroll
  for (int q = 0; q < 4; ++q) {
    int u = t + q * 64;
    float r = re[u], m = im[u];
    magp[(size_t)u * WW + k] = sqrtf(r * r + m * m) * scale;
    php[(size_t)u * WW + k]  = atan2f(m, r);
  }
}

// ----------------------------------------------------------------
extern "C" void kernel_launch(void* const* d_in, const int* in_sizes, int n_in,
                              void* d_out, int out_size, void* d_ws, size_t ws_size,
                              hipStream_t stream) {
  const float* x  = (const float*)d_in[0];
  const float* wk = (const float*)d_in[1];
  float* out = (float*)d_out;

  // FFT staging reuses the gabor output region (overwritten by conv later on
  // the same stream, so ordering is safe).
  float* stg = out + GAB_OFF;

  fft_rows_kernel<<<dim3(BB * CC * HH), dim3(64), 0, stream>>>(x, stg);
  fft_cols_kernel<<<dim3(BB * CC * WW), dim3(64), 0, stream>>>(stg, out + FFT_OFF);
  gabor_conv_kernel<<<dim3(64, CC, BB), dim3(256), 0, stream>>>(x, wk, out);
  haar_dwt_kernel<<<dim3(1536), dim3(256), 0, stream>>>(x, out);
}

// Round 2
// 197.549 us; speedup vs baseline: 3.8691x; 3.8691x over previous
//
#include <hip/hip_runtime.h>
#include <math.h>

#define BB 8
#define CC 3
#define HH 256
#define WW 256
#define KSZ 37
#define PD 18

#define DWT_OFF 0
#define GAB_OFF (8*12*128*128)                 /* 1572864 */
#define FFT_OFF (GAB_OFF + 8*54*256*256)       /* 29884416 */

typedef short bf16x8 __attribute__((ext_vector_type(8)));
typedef float f32x16 __attribute__((ext_vector_type(16)));

__device__ __forceinline__ unsigned f2bf(float f) {
  unsigned u = __float_as_uint(f);
  return (u + 0x7fffu + ((u >> 16) & 1u)) >> 16;   // RNE bf16
}

// ------------------------------------------------- filter prep: 8 shifted
// bf16 copies, Wsh[s][ky][32 m][48 kx'], zero-padded (m>=18 or kx'-s outside)
__global__ __launch_bounds__(256) void prep_wsh_kernel(
    const float* __restrict__ wk, ushort* __restrict__ wsh) {
  int idx = blockIdx.x * 256 + threadIdx.x;      // 8*37*32*48 = 454656
  if (idx >= 454656) return;
  int kx = idx % 48; int tmp = idx / 48;
  int m = tmp % 32; tmp /= 32;
  int ky = tmp % 37; int s = tmp / 37;
  int kk = kx - s;
  float v = 0.0f;
  if (m < 18 && kk >= 0 && kk < 37) v = wk[(m * 37 + ky) * 37 + kk];
  wsh[idx] = (ushort)f2bf(v);
}

// ------------------------------------------------- Gabor conv via MFMA
// Block: 512 thr (8 waves), tile 32y x 32x, all 18 filters.
// Wave w owns columns {w, w+8, w+16, w+24}; uses Wsh shift s=w.
__global__ __launch_bounds__(512) void gabor_mfma_kernel(
    const float* __restrict__ x, const ushort* __restrict__ wsh,
    float* __restrict__ out) {
  __shared__ unsigned patchU[68 * 40];           // 68 rows x 80 bf16
  __shared__ float cbuf[4 * 32 * 33];            // C transpose buffer

  const int tid = threadIdx.x;
  const int tileX = (blockIdx.x & 7) * 32;
  const int tileY = (blockIdx.x >> 3) * 32;
  const int cin = blockIdx.y, b = blockIdx.z;
  const float* xp = x + (size_t)(b * CC + cin) * (HH * WW);

  // ---- stage 68x80 bf16 patch, zero borders
  for (int idx = tid; idx < 68 * 40; idx += 512) {
    int r = idx / 40, dc = idx - r * 40;
    int gy = tileY + r - PD;
    int gx0 = tileX + 2 * dc - PD;
    float v0 = 0.0f, v1 = 0.0f;
    if ((unsigned)gy < 256u) {
      if ((unsigned)gx0 < 256u)       v0 = xp[gy * WW + gx0];
      if ((unsigned)(gx0 + 1) < 256u) v1 = xp[gy * WW + gx0 + 1];
    }
    patchU[idx] = f2bf(v0) | (f2bf(v1) << 16);
  }
  __syncthreads();

  const int w  = tid >> 6;
  const int l  = tid & 63;
  const int n  = l & 31;        // pixel y within tile / A filter row
  const int hi = l >> 5;        // k-half selector

  f32x16 acc0 = {0.f,0.f,0.f,0.f,0.f,0.f,0.f,0.f,0.f,0.f,0.f,0.f,0.f,0.f,0.f,0.f};
  f32x16 acc1 = acc0, acc2 = acc0, acc3 = acc0;

  const ushort* patchS = reinterpret_cast<const ushort*>(patchU);
  const ushort* arow = wsh + (size_t)w * (37 * 32 * 48) + (size_t)n * 48 + hi * 8;
  const ushort* brow = patchS + (size_t)n * 80 + hi * 8;

  for (int ky = 0; ky < 37; ++ky) {
#pragma unroll
    for (int t = 0; t < 3; ++t) {
      bf16x8 a  = *reinterpret_cast<const bf16x8*>(arow + 16 * t);
      bf16x8 b0 = *reinterpret_cast<const bf16x8*>(brow + 16 * t);
      bf16x8 b1 = *reinterpret_cast<const bf16x8*>(brow + 16 * t + 8);
      bf16x8 b2 = *reinterpret_cast<const bf16x8*>(brow + 16 * t + 16);
      bf16x8 b3 = *reinterpret_cast<const bf16x8*>(brow + 16 * t + 24);
      acc0 = __builtin_amdgcn_mfma_f32_32x32x16_bf16(a, b0, acc0, 0, 0, 0);
      acc1 = __builtin_amdgcn_mfma_f32_32x32x16_bf16(a, b1, acc1, 0, 0, 0);
      acc2 = __builtin_amdgcn_mfma_f32_32x32x16_bf16(a, b2, acc2, 0, 0, 0);
      acc3 = __builtin_amdgcn_mfma_f32_32x32x16_bf16(a, b3, acc3, 0, 0, 0);
    }
    arow += 32 * 48;
    brow += 80;
  }
  __syncthreads();

  // ---- epilogue: transpose C through LDS, coalesced stores
  // C row f' = (reg&3) + 8*(reg>>2) + 4*hi ; col = n (pixel y)
  float* outb = out + GAB_OFF + (size_t)(b * 54 + cin * 18) * (HH * WW);
#pragma unroll
  for (int g = 0; g < 5; ++g) {                  // f' groups [4g,4g+4), f'<20
    if (hi == (g & 1)) {
      const int rq = g >> 1;
#pragma unroll
      for (int q = 0; q < 4; ++q) {
        const int e = 4 * rq + q;
        float* crow = &cbuf[(q * 32 + n) * 33 + w];
        crow[0]  = acc0[e];
        crow[8]  = acc1[e];
        crow[16] = acc2[e];
        crow[24] = acc3[e];
      }
    }
    __syncthreads();
#pragma unroll
    for (int it = 0; it < 8; ++it) {
      int idx = tid + it * 512;                  // 4096 = 4f x 32y x 32x
      int xo = idx & 31, yo = (idx >> 5) & 31, q = idx >> 10;
      int f = 4 * g + q;
      if (f < 18)
        outb[(size_t)f * (HH * WW) + (size_t)(tileY + yo) * WW + tileX + xo] =
            cbuf[(q * 32 + yo) * 33 + xo];
    }
    __syncthreads();
  }
}

// ---------------------------------------------------------------- Haar DWT
__global__ __launch_bounds__(256) void haar_dwt_kernel(
    const float* __restrict__ x, float* __restrict__ out) {
  int idx = blockIdx.x * 256 + threadIdx.x;
  if (idx >= BB * CC * 128 * 128) return;
  int j  = idx & 127;
  int i  = (idx >> 7) & 127;
  int bc = idx >> 14;
  const float* xp = x + (size_t)bc * (HH * WW);
  float2 top = *reinterpret_cast<const float2*>(&xp[(2 * i) * WW + 2 * j]);
  float2 bot = *reinterpret_cast<const float2*>(&xp[(2 * i + 1) * WW + 2 * j]);
  float a = top.x, b = top.y, c = bot.x, d = bot.y;
  int bI = bc / 3, cI = bc % 3;
  float* op = out + DWT_OFF + ((size_t)(bI * 12 + cI * 4) * 128 + i) * 128 + j;
  op[0]     = (a + b + c + d) * 0.5f;
  op[16384] = (a + b - c - d) * 0.5f;
  op[32768] = (a - b + c - d) * 0.5f;
  op[49152] = (a - b - c + d) * 0.5f;
}

// ---------------------------------------------------------------- FFT pass A
__global__ __launch_bounds__(64) void fft_rows_kernel(
    const float* __restrict__ x, float* __restrict__ stg) {
  __shared__ float re[256], im[256];
  const int rowid = blockIdx.x;
  const float* xr = x + (size_t)rowid * 256;
  const int t = threadIdx.x;

#pragma unroll
  for (int q = 0; q < 4; ++q) {
    int i = t + q * 64;
    int br = __brev((unsigned)i) >> 24;
    re[br] = xr[i];
    im[br] = 0.0f;
  }
  __syncthreads();

  for (int s = 1; s <= 8; ++s) {
    int half = 1 << (s - 1);
#pragma unroll
    for (int q = 0; q < 2; ++q) {
      int j = t + q * 64;
      int g = j >> (s - 1);
      int p = j & (half - 1);
      int i1 = (g << s) + p;
      int i2 = i1 + half;
      float ang = -(float)M_PI * (float)p / (float)half;
      float sn, cs;
      sincosf(ang, &sn, &cs);
      float r2 = re[i2], m2 = im[i2];
      float tr = r2 * cs - m2 * sn;
      float ti = r2 * sn + m2 * cs;
      float r1 = re[i1], m1 = im[i1];
      re[i2] = r1 - tr; im[i2] = m1 - ti;
      re[i1] = r1 + tr; im[i1] = m1 + ti;
    }
    __syncthreads();
  }

  float* sr = stg + (size_t)rowid * 258;
#pragma unroll
  for (int q = 0; q < 3; ++q) {
    int k = t + q * 64;
    if (k <= 128) {
      sr[2 * k]     = re[k];
      sr[2 * k + 1] = im[k];
    }
  }
}

// ---------------------------------------------------------------- FFT pass B
__global__ __launch_bounds__(64) void fft_cols_kernel(
    const float* __restrict__ stg, float* __restrict__ outf) {
  const int k  = blockIdx.x & 255;
  const int bc = blockIdx.x >> 8;
  const int b  = bc / 3;
  const int c  = bc - b * 3;
  const int t  = threadIdx.x;
  float* magp = outf + (size_t)(b * 6 + c) * (HH * WW);
  float* php  = outf + (size_t)(b * 6 + c + 3) * (HH * WW);

  if (k >= 129) {
#pragma unroll
    for (int q = 0; q < 4; ++q) {
      int u = t + q * 64;
      magp[(size_t)u * WW + k] = 0.0f;
      php[(size_t)u * WW + k]  = 0.0f;
    }
    return;
  }

  __shared__ float re[256], im[256];
  const float* sp = stg + (size_t)bc * (256 * 258);
#pragma unroll
  for (int q = 0; q < 4; ++q) {
    int y = t + q * 64;
    int br = __brev((unsigned)y) >> 24;
    re[br] = sp[(size_t)y * 258 + 2 * k];
    im[br] = sp[(size_t)y * 258 + 2 * k + 1];
  }
  __syncthreads();

  for (int s = 1; s <= 8; ++s) {
    int half = 1 << (s - 1);
#pragma unroll
    for (int q = 0; q < 2; ++q) {
      int j = t + q * 64;
      int g = j >> (s - 1);
      int p = j & (half - 1);
      int i1 = (g << s) + p;
      int i2 = i1 + half;
      float ang = -(float)M_PI * (float)p / (float)half;
      float sn, cs;
      sincosf(ang, &sn, &cs);
      float r2 = re[i2], m2 = im[i2];
      float tr = r2 * cs - m2 * sn;
      float ti = r2 * sn + m2 * cs;
      float r1 = re[i1], m1 = im[i1];
      re[i2] = r1 - tr; im[i2] = m1 - ti;
      re[i1] = r1 + tr; im[i1] = m1 + ti;
    }
    __syncthreads();
  }

  const float scale = 1.0f / 256.0f;
#pragma unroll
  for (int q = 0; q < 4; ++q) {
    int u = t + q * 64;
    float r = re[u], m = im[u];
    magp[(size_t)u * WW + k] = sqrtf(r * r + m * m) * scale;
    php[(size_t)u * WW + k]  = atan2f(m, r);
  }
}

// ----------------------------------------------------------------
extern "C" void kernel_launch(void* const* d_in, const int* in_sizes, int n_in,
                              void* d_out, int out_size, void* d_ws, size_t ws_size,
                              hipStream_t stream) {
  const float* x  = (const float*)d_in[0];
  const float* wk = (const float*)d_in[1];
  float* out = (float*)d_out;

  // Scratch regions inside d_out (stream-serialized, overwritten later):
  //  - shifted bf16 filters in the DWT region (DWT kernel runs last)
  //  - FFT row staging in the gabor region (conv runs after fft_cols)
  ushort* wsh = (ushort*)(out + DWT_OFF);        // 909 KB < 6.29 MB
  float*  stg = out + GAB_OFF;

  prep_wsh_kernel<<<dim3(1776), dim3(256), 0, stream>>>(wk, wsh);
  fft_rows_kernel<<<dim3(BB * CC * HH), dim3(64), 0, stream>>>(x, stg);
  fft_cols_kernel<<<dim3(BB * CC * WW), dim3(64), 0, stream>>>(stg, out + FFT_OFF);
  gabor_mfma_kernel<<<dim3(64, CC, BB), dim3(512), 0, stream>>>(x, wsh, out);
  haar_dwt_kernel<<<dim3(1536), dim3(256), 0, stream>>>(x, out);
}